// Round 9
// baseline (268.305 us; speedup 1.0000x reference)
//
#include <hip/hip_runtime.h>
#include <math.h>

// TopKRouter: logits = x(16384x2048) @ W(2048x64) + b; softmax E=64; top-2.
// Output: d_out[0:32768] = indices (as float), d_out[32768:65536] = probs.
//
// R8: occupancy fix. R7 counters (router 78us, hbm 11%, MfmaUtil 6%,
// VALUBusy 9%, Occupancy 17%) = latency-bound at 2 blocks/CU (grid 512).
// Keep R7's LDS-free per-lane loop (global->reg->mask+pkrtz->MFMA, no
// barriers); shrink block work: RM=16, grid=1024, wave=(ew expert-half x
// kw K-half): 32 k-steps x 6 MFMA. Regs: acc 16 + x depth-4 32 + W pp 32
// ~= 105 -> __launch_bounds__(256,4) => 4 blocks/CU x 4 waves = 4 waves/SIMD
// (2x TLP). x prefetch depth 4 (~450cyc lookahead vs ~600-900 HBM). W L2
// traffic 256->512MB (~15-18us, overlaps x 21us HBM; R3/R4 showed lockstep
// not W-traffic was the old regression). Numerics identical (absmax 2^-10).
// R8b: identical resubmission — R8 bench failed at GPU acquisition.

#define D_DIM 2048
#define E_DIM 64
#define M_DIM 16384
#define RM 16             // token rows per block

typedef _Float16 half8 __attribute__((ext_vector_type(8)));
typedef float floatx4 __attribute__((ext_vector_type(4)));
typedef unsigned int uint;

// ---------------- kernel 1: W split into fragment-linear layout (unchanged) ----
// For k-step g (32 k), tile t, plane p (0=hi,1=lo):
//   wsT[((g*4+t)*2+p)*512 + lane*8 + j] = plane(W[g*32 + quad*8 + j][16t + c]),
//   lane = quad*16 + c.
__global__ __launch_bounds__(256) void split_w_kernel(
    const float* __restrict__ Wm, _Float16* __restrict__ wsT)
{
    const int tid = threadIdx.x;
    const int n   = tid & 63;
    const int kk0 = tid >> 6;           // 0..3
    const int g   = blockIdx.x;         // 0..63
    #pragma unroll
    for (int r = 0; r < 8; r++) {
        const int kk = kk0 + r * 4;     // 0..31
        const float v = Wm[(size_t)(g * 32 + kk) * E_DIM + n];
        const _Float16 h = (_Float16)v;
        const _Float16 l = (_Float16)((v - (float)h) * 2048.0f);
        const int t = n >> 4, cc = n & 15, qd = kk >> 3, j = kk & 7;
        const size_t base = (size_t)((g * 4 + t) * 2) * 512 + (size_t)(qd * 16 + cc) * 8 + j;
        wsT[base]       = h;
        wsT[base + 512] = l;
    }
}

// ---------------- kernel 2: LDS-free MFMA GEMM + softmax + top-2 ----------------
__global__ __launch_bounds__(256, 4) void router_mfma_kernel(
    const float* __restrict__ x, const _Float16* __restrict__ wsT,
    const float* __restrict__ bias, float* __restrict__ out)
{
    __shared__ float red[2 * RM * 65];    // [kw][row][expert(+pad)] 8320 B

    const int lane = threadIdx.x & 63;
    const int wave = threadIdx.x >> 6;    // 0..3
    const int ew   = wave & 1;            // expert half: tiles 2*ew, 2*ew+1
    const int kw   = wave >> 1;           // K half: k in [kw*1024, kw*1024+1024)
    const int c    = lane & 15;
    const int quad = lane >> 4;
    const int r0   = blockIdx.x * RM;

    // x B-frag source: lane (c,quad) reads x[r0 + c][kw*1024 + u*32 + quad*8 .. +7]
    const float* xg = x + (size_t)(r0 + c) * D_DIM + kw * 1024 + quad * 8;
    // W A-frags: g = kw*32 + u; wsT[g*4096 + tile*1024 + plane*512 + lane*8]
    const _Float16* wbase = wsT + (size_t)(kw * 32) * 4096
                                + (size_t)(ew * 2) * 1024 + (size_t)lane * 8;

    floatx4 accm[2] = {};   // [tile t]  expert = (ew*2+t)*16 + quad*4 + i, col = c
    floatx4 accl[2] = {};

    float4 q0[2], q1[2], q2[2], q3[2];    // x prefetch, depth 4
    half8 whA[2], wlA[2], whB[2], wlB[2]; // W ping-pong

    auto loadx = [&](int u, float4* q) {
        const int uu = u < 32 ? u : 31;   // clamp (redundant L2-hit loads)
        q[0] = *reinterpret_cast<const float4*>(xg + uu * 32);
        q[1] = *reinterpret_cast<const float4*>(xg + uu * 32 + 4);
    };
    auto loadW = [&](int u, half8* wh, half8* wl) {
        const int uu = u < 32 ? u : 31;
        const _Float16* p = wbase + (size_t)uu * 4096;
        wh[0] = *reinterpret_cast<const half8*>(p);
        wl[0] = *reinterpret_cast<const half8*>(p + 512);
        wh[1] = *reinterpret_cast<const half8*>(p + 1024);
        wl[1] = *reinterpret_cast<const half8*>(p + 1024 + 512);
    };
    // fp32x8 -> (hi fp16x8, lo fp16x8); h = 13-bit-masked (exact in fp16),
    // l = (v-h)*2048 (exact). Proven numerics (R5/R7, absmax 2^-10).
    auto mkfrag = [&](const float4& u0, const float4& u1, half8& h8, half8& l8) {
        const float f[8] = {u0.x, u0.y, u0.z, u0.w, u1.x, u1.y, u1.z, u1.w};
        uint hq[4], lq[4];
        #pragma unroll
        for (int p = 0; p < 4; p++) {
            const float f0 = f[2 * p], f1 = f[2 * p + 1];
            const float h0 = __uint_as_float(__float_as_uint(f0) & 0xFFFFE000u);
            const float h1 = __uint_as_float(__float_as_uint(f1) & 0xFFFFE000u);
            hq[p] = __builtin_bit_cast(uint, __builtin_amdgcn_cvt_pkrtz(h0, h1));
            lq[p] = __builtin_bit_cast(uint,
                        __builtin_amdgcn_cvt_pkrtz((f0 - h0) * 2048.0f, (f1 - h1) * 2048.0f));
        }
        h8 = __builtin_bit_cast(half8, make_uint4(hq[0], hq[1], hq[2], hq[3]));
        l8 = __builtin_bit_cast(half8, make_uint4(lq[0], lq[1], lq[2], lq[3]));
    };
    // D = A(W) * B(x); split-3: Wh*xh -> m, Wh*xl + Wl*xh -> l
    auto step = [&](const float4* q, const half8* wh, const half8* wl) {
        half8 xh, xl;
        mkfrag(q[0], q[1], xh, xl);
        #pragma unroll
        for (int t = 0; t < 2; t++) {
            accm[t] = __builtin_amdgcn_mfma_f32_16x16x32_f16(wh[t], xh, accm[t], 0, 0, 0);
            accl[t] = __builtin_amdgcn_mfma_f32_16x16x32_f16(wh[t], xl, accl[t], 0, 0, 0);
            accl[t] = __builtin_amdgcn_mfma_f32_16x16x32_f16(wl[t], xh, accl[t], 0, 0, 0);
        }
    };

    // prologue: 4 x-steps + W(0) in flight
    loadx(0, q0); loadx(1, q1); loadx(2, q2); loadx(3, q3);
    loadW(0, whA, wlA);

    #pragma unroll 1
    for (int u = 0; u < 32; u += 4) {
        loadW(u + 1, whB, wlB);
        step(q0, whA, wlA);  loadx(u + 4, q0);
        loadW(u + 2, whA, wlA);
        step(q1, whB, wlB);  loadx(u + 5, q1);
        loadW(u + 3, whB, wlB);
        step(q2, whA, wlA);  loadx(u + 6, q2);
        loadW(u + 4, whA, wlA);
        step(q3, whB, wlB);  loadx(u + 7, q3);
    }

    // ---- K-split partials -> LDS ----
    const float scale = 1.0f / 2048.0f;
    #pragma unroll
    for (int t = 0; t < 2; t++)
        #pragma unroll
        for (int i = 0; i < 4; i++)
            red[(kw * 16 + c) * 65 + (ew * 2 + t) * 16 + quad * 4 + i] =
                accm[t][i] + accl[t][i] * scale;
    __syncthreads();

    if (wave != 0) return;

    float bvt[4];
    #pragma unroll
    for (int t = 0; t < 4; t++) bvt[t] = bias[c + 16 * t];

    #pragma unroll
    for (int i = 0; i < 4; i++) {
        const int row = quad * 4 + i;
        float lt[4];
        #pragma unroll
        for (int t = 0; t < 4; t++) {
            const int col = c + 16 * t;
            lt[t] = red[(0 * 16 + row) * 65 + col] + red[(1 * 16 + row) * 65 + col] + bvt[t];
        }
        const float l0 = lt[0], l1 = lt[1], l2 = lt[2], l3 = lt[3];

        float m = fmaxf(fmaxf(l0, l1), fmaxf(l2, l3));
        #pragma unroll
        for (int off = 1; off < 16; off <<= 1)
            m = fmaxf(m, __shfl_xor(m, off, 64));

        const float e0 = expf(l0 - m), e1 = expf(l1 - m);
        const float e2 = expf(l2 - m), e3 = expf(l3 - m);
        float s = e0 + e1 + e2 + e3;
        #pragma unroll
        for (int off = 1; off < 16; off <<= 1)
            s += __shfl_xor(s, off, 64);

        const float p0 = e0 / s, p1 = e1 / s, p2 = e2 / s, p3 = e3 / s;

        // keys: (prob bits << 32) | (63 - expert); experts c, c+16, c+32, c+48
        const unsigned long long ka =
            ((unsigned long long)__float_as_uint(p0) << 32) | (unsigned long long)(63 - c);
        const unsigned long long kb_ =
            ((unsigned long long)__float_as_uint(p1) << 32) | (unsigned long long)(47 - c);
        const unsigned long long kc_ =
            ((unsigned long long)__float_as_uint(p2) << 32) | (unsigned long long)(31 - c);
        const unsigned long long kd =
            ((unsigned long long)__float_as_uint(p3) << 32) | (unsigned long long)(15 - c);

        unsigned long long hi1 = ka > kb_ ? ka : kb_, lo1 = ka > kb_ ? kb_ : ka;
        unsigned long long hi2 = kc_ > kd ? kc_ : kd, lo2 = kc_ > kd ? kd : kc_;
        unsigned long long k1 = hi1 > hi2 ? hi1 : hi2;
        unsigned long long mn = hi1 > hi2 ? hi2 : hi1;
        unsigned long long mx = lo1 > lo2 ? lo1 : lo2;
        unsigned long long k2 = mn > mx ? mn : mx;

        #pragma unroll
        for (int off = 1; off < 16; off <<= 1) {
            const unsigned long long o1 = __shfl_xor(k1, off, 64);
            const unsigned long long o2 = __shfl_xor(k2, off, 64);
            const unsigned long long n1 = k1 > o1 ? k1 : o1;
            const unsigned long long w1 = k1 > o1 ? o1 : k1;   // loser of firsts
            const unsigned long long w2 = k2 > o2 ? k2 : o2;   // best of seconds
            k1 = n1;
            k2 = w1 > w2 ? w1 : w2;
        }

        if (c == 0) {
            const int gr = r0 + row;
            out[gr * 2 + 0] = (float)(63 - (int)(k1 & 0xFFFFFFFFull));
            out[gr * 2 + 1] = (float)(63 - (int)(k2 & 0xFFFFFFFFull));
            out[M_DIM * 2 + gr * 2 + 0] = __uint_as_float((unsigned)(k1 >> 32));
            out[M_DIM * 2 + gr * 2 + 1] = __uint_as_float((unsigned)(k2 >> 32));
        }
    }
}

extern "C" void kernel_launch(void* const* d_in, const int* in_sizes, int n_in,
                              void* d_out, int out_size, void* d_ws, size_t ws_size,
                              hipStream_t stream) {
    const float* x  = (const float*)d_in[0];
    const float* Wm = (const float*)d_in[1];
    const float* b  = (const float*)d_in[2];
    float* out = (float*)d_out;
    _Float16* wsT = (_Float16*)d_ws;   // 64*4*2*512*2 B = 512 KB

    split_w_kernel<<<dim3(64), dim3(256), 0, stream>>>(Wm, wsT);
    router_mfma_kernel<<<dim3(M_DIM / RM), dim3(256), 0, stream>>>(x, wsT, b, out);
}

// Round 10
// 201.265 us; speedup vs baseline: 1.3331x; 1.3331x over previous
//
#include <hip/hip_runtime.h>
#include <math.h>

// TopKRouter: logits = x(16384x2048) @ W(2048x64) + b; softmax E=64; top-2.
// Output: d_out[0:32768] = indices (as float), d_out[32768:65536] = probs.
//
// R10: R7 base (best LDS-free router, 78us) + sched_barrier(0) pins.
// Evidence: R7 declared ~190 live VGPRs for its depth-2 W ping-pong +
// depth-2 x prefetch but measured VGPR_Count=92; R8 declared ~80+, measured
// 60. The compiler SANK the prefetch loads to their uses (pressure heuristic),
// collapsing the pipeline -> every step exposes full L2/L3 latency serially.
// Explains R8's paradox (occupancy 17->31% yet hbm 900->560 GB/s, 78->130us):
// more waves, each fully serialized. Fix: pin load-issue points with
// __builtin_amdgcn_sched_barrier(0) (scheduling fence only, no codegen
// semantics change). Geometry/numerics identical to R7 (absmax 2^-10).
// Falsifier: VGPR_Count must jump >=160 if pins held.

#define D_DIM 2048
#define E_DIM 64
#define M_DIM 16384
#define RM 32             // token rows per block (2 row-groups x 16)

typedef _Float16 half8 __attribute__((ext_vector_type(8)));
typedef float floatx4 __attribute__((ext_vector_type(4)));
typedef unsigned int uint;

#define SBAR() __builtin_amdgcn_sched_barrier(0)

// ---------------- kernel 1: W split into fragment-linear layout (unchanged) ----
// For k-step g (32 k), tile t, plane p (0=hi,1=lo):
//   wsT[((g*4+t)*2+p)*512 + lane*8 + j] = plane(W[g*32 + quad*8 + j][16t + c]),
//   lane = quad*16 + c.
__global__ __launch_bounds__(256) void split_w_kernel(
    const float* __restrict__ Wm, _Float16* __restrict__ wsT)
{
    const int tid = threadIdx.x;
    const int n   = tid & 63;
    const int kk0 = tid >> 6;           // 0..3
    const int g   = blockIdx.x;         // 0..63
    #pragma unroll
    for (int r = 0; r < 8; r++) {
        const int kk = kk0 + r * 4;     // 0..31
        const float v = Wm[(size_t)(g * 32 + kk) * E_DIM + n];
        const _Float16 h = (_Float16)v;
        const _Float16 l = (_Float16)((v - (float)h) * 2048.0f);
        const int t = n >> 4, cc = n & 15, qd = kk >> 3, j = kk & 7;
        const size_t base = (size_t)((g * 4 + t) * 2) * 512 + (size_t)(qd * 16 + cc) * 8 + j;
        wsT[base]       = h;
        wsT[base + 512] = l;
    }
}

// ---------------- kernel 2: LDS-free MFMA GEMM + softmax + top-2 ----------------
__global__ __launch_bounds__(256, 2) void router_mfma_kernel(
    const float* __restrict__ x, const _Float16* __restrict__ wsT,
    const float* __restrict__ bias, float* __restrict__ out)
{
    __shared__ float red[4 * RM * 65];    // [kwave][row][expert(+pad)] 33280 B

    const int lane = threadIdx.x & 63;
    const int wave = threadIdx.x >> 6;    // k-split: wave w owns k in [w*512, w*512+512)
    const int c    = lane & 15;
    const int quad = lane >> 4;
    const int r0   = blockIdx.x * RM;
    const int kb   = wave * (D_DIM / 4);  // 512

    // x B-frag source: lane (c,quad) reads x[r0 + rg*16 + c][kb + u*32 + quad*8 .. +7]
    const float* xg0 = x + (size_t)(r0 + c) * D_DIM + kb + quad * 8;
    const float* xg1 = xg0 + (size_t)16 * D_DIM;
    // W A-frags: wsT[(wave*16 + u)*4096 + t*1024 + plane*512 + lane*8 + j]
    const _Float16* wbase = wsT + (size_t)(wave * 16) * 4096 + (size_t)lane * 8;

    floatx4 accm[2][4] = {};   // [row-group][expert tile]
    floatx4 accl[2][4] = {};

    float4 a0A, a1A, b0A, b1A;   // ping x regs (rg0 pair, rg1 pair)
    float4 a0B, a1B, b0B, b1B;   // pong
    half8 wh0[4], wl0[4], wh1[4], wl1[4];

    auto loadxA = [&](int u) {
        const int uu = u < 16 ? u : 15;
        a0A = *reinterpret_cast<const float4*>(xg0 + uu * 32);
        a1A = *reinterpret_cast<const float4*>(xg0 + uu * 32 + 4);
        b0A = *reinterpret_cast<const float4*>(xg1 + uu * 32);
        b1A = *reinterpret_cast<const float4*>(xg1 + uu * 32 + 4);
    };
    auto loadxB = [&](int u) {
        const int uu = u < 16 ? u : 15;
        a0B = *reinterpret_cast<const float4*>(xg0 + uu * 32);
        a1B = *reinterpret_cast<const float4*>(xg0 + uu * 32 + 4);
        b0B = *reinterpret_cast<const float4*>(xg1 + uu * 32);
        b1B = *reinterpret_cast<const float4*>(xg1 + uu * 32 + 4);
    };
    auto loadW = [&](int u, half8* wh, half8* wl) {   // u = local k-step 0..15
        const int uu = u < 16 ? u : 15;
        const _Float16* p = wbase + (size_t)uu * 4096;
        #pragma unroll
        for (int t = 0; t < 4; t++) {
            wh[t] = *reinterpret_cast<const half8*>(p + t * 1024);
            wl[t] = *reinterpret_cast<const half8*>(p + t * 1024 + 512);
        }
    };
    // fp32x8 -> (hi fp16x8, lo fp16x8); h = RTZ-13-bit-masked (exact in fp16),
    // l = (v-h)*2048 (exact product of residual). Proven numerics (R5/R7).
    auto mkfrag = [&](const float4& u0, const float4& u1, half8& h8, half8& l8) {
        const float f[8] = {u0.x, u0.y, u0.z, u0.w, u1.x, u1.y, u1.z, u1.w};
        uint hq[4], lq[4];
        #pragma unroll
        for (int p = 0; p < 4; p++) {
            const float f0 = f[2 * p], f1 = f[2 * p + 1];
            const float h0 = __uint_as_float(__float_as_uint(f0) & 0xFFFFE000u);
            const float h1 = __uint_as_float(__float_as_uint(f1) & 0xFFFFE000u);
            hq[p] = __builtin_bit_cast(uint, __builtin_amdgcn_cvt_pkrtz(h0, h1));
            lq[p] = __builtin_bit_cast(uint,
                        __builtin_amdgcn_cvt_pkrtz((f0 - h0) * 2048.0f, (f1 - h1) * 2048.0f));
        }
        h8 = __builtin_bit_cast(half8, make_uint4(hq[0], hq[1], hq[2], hq[3]));
        l8 = __builtin_bit_cast(half8, make_uint4(lq[0], lq[1], lq[2], lq[3]));
    };
    // D = A(W) * B(x): accm/accl[rg][t]; split-3: Wh*xh -> m, Wh*xl + Wl*xh -> l
    auto stepA = [&](const half8* wh, const half8* wl) {
        half8 xh0, xl0, xh1, xl1;
        mkfrag(a0A, a1A, xh0, xl0);
        mkfrag(b0A, b1A, xh1, xl1);
        #pragma unroll
        for (int t = 0; t < 4; t++) {
            accm[0][t] = __builtin_amdgcn_mfma_f32_16x16x32_f16(wh[t], xh0, accm[0][t], 0, 0, 0);
            accl[0][t] = __builtin_amdgcn_mfma_f32_16x16x32_f16(wh[t], xl0, accl[0][t], 0, 0, 0);
            accl[0][t] = __builtin_amdgcn_mfma_f32_16x16x32_f16(wl[t], xh0, accl[0][t], 0, 0, 0);
            accm[1][t] = __builtin_amdgcn_mfma_f32_16x16x32_f16(wh[t], xh1, accm[1][t], 0, 0, 0);
            accl[1][t] = __builtin_amdgcn_mfma_f32_16x16x32_f16(wh[t], xl1, accl[1][t], 0, 0, 0);
            accl[1][t] = __builtin_amdgcn_mfma_f32_16x16x32_f16(wl[t], xh1, accl[1][t], 0, 0, 0);
        }
    };
    auto stepB = [&](const half8* wh, const half8* wl) {
        half8 xh0, xl0, xh1, xl1;
        mkfrag(a0B, a1B, xh0, xl0);
        mkfrag(b0B, b1B, xh1, xl1);
        #pragma unroll
        for (int t = 0; t < 4; t++) {
            accm[0][t] = __builtin_amdgcn_mfma_f32_16x16x32_f16(wh[t], xh0, accm[0][t], 0, 0, 0);
            accl[0][t] = __builtin_amdgcn_mfma_f32_16x16x32_f16(wh[t], xl0, accl[0][t], 0, 0, 0);
            accl[0][t] = __builtin_amdgcn_mfma_f32_16x16x32_f16(wl[t], xh0, accl[0][t], 0, 0, 0);
            accm[1][t] = __builtin_amdgcn_mfma_f32_16x16x32_f16(wh[t], xh1, accm[1][t], 0, 0, 0);
            accl[1][t] = __builtin_amdgcn_mfma_f32_16x16x32_f16(wh[t], xl1, accl[1][t], 0, 0, 0);
            accl[1][t] = __builtin_amdgcn_mfma_f32_16x16x32_f16(wl[t], xh1, accl[1][t], 0, 0, 0);
        }
    };

    // prologue: steps 0,1 in regs; W(0) in flight — pinned at issue point
    loadxA(0);
    loadxB(1);
    loadW(0, wh0, wl0);
    SBAR();

    #pragma unroll 1
    for (int u = 0; u < 16; u += 2) {
        loadW(u + 1, wh1, wl1);     // W for step u+1: one full step of slack
        SBAR();                     // pin: loads above may not sink below
        stepA(wh0, wl0);            // k-step u
        loadxA(u + 2);              // x two steps ahead
        SBAR();
        loadW(u + 2, wh0, wl0);
        SBAR();
        stepB(wh1, wl1);            // k-step u+1
        loadxB(u + 3);
        SBAR();
    }

    // ---- K-split partials -> LDS ----
    const float scale = 1.0f / 2048.0f;
    #pragma unroll
    for (int rg = 0; rg < 2; rg++)
        #pragma unroll
        for (int t = 0; t < 4; t++)
            #pragma unroll
            for (int i = 0; i < 4; i++)
                red[(wave * 32 + rg * 16 + c) * 65 + t * 16 + quad * 4 + i] =
                    accm[rg][t][i] + accl[rg][t][i] * scale;
    __syncthreads();

    if (wave >= 2) return;

    float bvt[4];
    #pragma unroll
    for (int t = 0; t < 4; t++) bvt[t] = bias[c + 16 * t];

    #pragma unroll
    for (int i = 0; i < 4; i++) {
        const int row = wave * 16 + quad * 4 + i;
        float lt[4];
        #pragma unroll
        for (int t = 0; t < 4; t++) {
            const int col = c + 16 * t;
            lt[t] = red[(0 * 32 + row) * 65 + col] + red[(1 * 32 + row) * 65 + col]
                  + red[(2 * 32 + row) * 65 + col] + red[(3 * 32 + row) * 65 + col] + bvt[t];
        }
        const float l0 = lt[0], l1 = lt[1], l2 = lt[2], l3 = lt[3];

        float m = fmaxf(fmaxf(l0, l1), fmaxf(l2, l3));
        #pragma unroll
        for (int off = 1; off < 16; off <<= 1)
            m = fmaxf(m, __shfl_xor(m, off, 64));

        const float e0 = expf(l0 - m), e1 = expf(l1 - m);
        const float e2 = expf(l2 - m), e3 = expf(l3 - m);
        float s = e0 + e1 + e2 + e3;
        #pragma unroll
        for (int off = 1; off < 16; off <<= 1)
            s += __shfl_xor(s, off, 64);

        const float p0 = e0 / s, p1 = e1 / s, p2 = e2 / s, p3 = e3 / s;

        // keys: (prob bits << 32) | (63 - expert); experts c, c+16, c+32, c+48
        const unsigned long long ka =
            ((unsigned long long)__float_as_uint(p0) << 32) | (unsigned long long)(63 - c);
        const unsigned long long kb_ =
            ((unsigned long long)__float_as_uint(p1) << 32) | (unsigned long long)(47 - c);
        const unsigned long long kc_ =
            ((unsigned long long)__float_as_uint(p2) << 32) | (unsigned long long)(31 - c);
        const unsigned long long kd =
            ((unsigned long long)__float_as_uint(p3) << 32) | (unsigned long long)(15 - c);

        unsigned long long hi1 = ka > kb_ ? ka : kb_, lo1 = ka > kb_ ? kb_ : ka;
        unsigned long long hi2 = kc_ > kd ? kc_ : kd, lo2 = kc_ > kd ? kd : kc_;
        unsigned long long k1 = hi1 > hi2 ? hi1 : hi2;
        unsigned long long mn = hi1 > hi2 ? hi2 : hi1;
        unsigned long long mx = lo1 > lo2 ? lo1 : lo2;
        unsigned long long k2 = mn > mx ? mn : mx;

        #pragma unroll
        for (int off = 1; off < 16; off <<= 1) {
            const unsigned long long o1 = __shfl_xor(k1, off, 64);
            const unsigned long long o2 = __shfl_xor(k2, off, 64);
            const unsigned long long n1 = k1 > o1 ? k1 : o1;
            const unsigned long long w1 = k1 > o1 ? o1 : k1;   // loser of firsts
            const unsigned long long w2 = k2 > o2 ? k2 : o2;   // best of seconds
            k1 = n1;
            k2 = w1 > w2 ? w1 : w2;
        }

        if (c == 0) {
            const int gr = r0 + row;
            out[gr * 2 + 0] = (float)(63 - (int)(k1 & 0xFFFFFFFFull));
            out[gr * 2 + 1] = (float)(63 - (int)(k2 & 0xFFFFFFFFull));
            out[M_DIM * 2 + gr * 2 + 0] = __uint_as_float((unsigned)(k1 >> 32));
            out[M_DIM * 2 + gr * 2 + 1] = __uint_as_float((unsigned)(k2 >> 32));
        }
    }
}

extern "C" void kernel_launch(void* const* d_in, const int* in_sizes, int n_in,
                              void* d_out, int out_size, void* d_ws, size_t ws_size,
                              hipStream_t stream) {
    const float* x  = (const float*)d_in[0];
    const float* Wm = (const float*)d_in[1];
    const float* b  = (const float*)d_in[2];
    float* out = (float*)d_out;
    _Float16* wsT = (_Float16*)d_ws;   // 64*4*2*512*2 B = 512 KB

    split_w_kernel<<<dim3(64), dim3(256), 0, stream>>>(Wm, wsT);
    router_mfma_kernel<<<dim3(M_DIM / RM), dim3(256), 0, stream>>>(x, wsT, b, out);
}